// Round 1
// baseline (310.827 us; speedup 1.0000x reference)
//
#include <hip/hip_runtime.h>
#include <hip/hip_bf16.h>

#define B_ 2
#define S_ 2048
#define D_ 1024
#define H_ 16
#define DKV_ 64
#define INNER_ 1024
#define M_ (B_*S_)   // 4096

typedef unsigned short ushort_t;
typedef __bf16 bf16x8 __attribute__((ext_vector_type(8)));
typedef float f32x4 __attribute__((ext_vector_type(4)));

__device__ __forceinline__ unsigned short f2bf(float f) {
    unsigned int u = __builtin_bit_cast(unsigned int, f);
    unsigned int r = (u + 0x7fffu + ((u >> 16) & 1u)) >> 16;
    return (unsigned short)r;
}

// ---------------- fp32 -> bf16 convert (hidden states) ----------------
__global__ __launch_bounds__(256) void cvt_bf16(const float* __restrict__ in,
                                                unsigned short* __restrict__ out, int n) {
    int i = (blockIdx.x * 256 + threadIdx.x) * 4;
    if (i < n) {
        float4 v = *(const float4*)&in[i];
        ushort4 o;
        o.x = f2bf(v.x); o.y = f2bf(v.y); o.z = f2bf(v.z); o.w = f2bf(v.w);
        *(ushort4*)&out[i] = o;
    }
}

// ---------------- transpose+convert weights: Wt[n][k] = (bf16)W[k][n] ----------------
__global__ __launch_bounds__(256) void transp_bf16(
        const float* __restrict__ s0, const float* __restrict__ s1,
        const float* __restrict__ s2, const float* __restrict__ s3,
        unsigned short* __restrict__ d0, unsigned short* __restrict__ d1,
        unsigned short* __restrict__ d2, unsigned short* __restrict__ d3) {
    const float* srcs[4] = {s0, s1, s2, s3};
    unsigned short* dsts[4] = {d0, d1, d2, d3};
    const float* src = srcs[blockIdx.z];
    unsigned short* dst = dsts[blockIdx.z];
    __shared__ float t[64][65];
    int k0 = blockIdx.y * 64, n0 = blockIdx.x * 64;
    for (int i = threadIdx.x; i < 4096; i += 256) {
        int r = i >> 6, c = i & 63;
        t[r][c] = src[(k0 + r) * 1024 + n0 + c];
    }
    __syncthreads();
    for (int i = threadIdx.x; i < 4096; i += 256) {
        int r = i >> 6, c = i & 63;
        dst[(n0 + r) * 1024 + k0 + c] = f2bf(t[c][r]);
    }
}

// ---------------- T5 relative bias table: btab[h][rel+2048] ----------------
__global__ __launch_bounds__(256) void bias_kernel(const float* __restrict__ rb,
                                                   float* __restrict__ btab) {
    int idx = blockIdx.x * 256 + threadIdx.x;   // 0..65535
    int h = idx >> 12, pos = idx & 4095;
    int rel = pos - 2048;
    int bb = rel > 0 ? 16 : 0;
    int rp = rel < 0 ? -rel : rel;
    int bucket;
    if (rp < 8) bucket = bb + rp;
    else {
        int v = 8 + (int)(logf((float)rp * 0.125f) / 2.7725887f * 8.0f);
        bucket = bb + (v < 15 ? v : 15);
    }
    btab[idx] = rb[bucket * 16 + h];
}

// ---------------- 128x128 MFMA GEMM, A [M][K] bf16, Bt [N][K] bf16 ----------------
// MODE 0: fp32 row-major [M][N]
// MODE 1: bf16 scatter [b][h][s][dkv]   (m = b*2048+s, n = h*64+d)
// MODE 2: bf16 scatter [b][h][dkv][s]   (V transposed)
template<int MODE>
__global__ __launch_bounds__(256) void gemm128(const unsigned short* __restrict__ A,
                                               const unsigned short* __restrict__ Bt,
                                               void* __restrict__ C,
                                               int M, int N, int K) {
    __shared__ alignas(16) unsigned short As[128][40];
    __shared__ alignas(16) unsigned short Bs[128][40];
    int tid = threadIdx.x;
    int m0 = blockIdx.y * 128, n0 = blockIdx.x * 128;
    int wid = tid >> 6, lane = tid & 63;
    int wm = (wid >> 1) * 64, wn = (wid & 1) * 64;
    int lr = lane & 15, lg = lane >> 4;
    f32x4 acc[4][4] = {};
    for (int kt = 0; kt < K; kt += 32) {
        #pragma unroll
        for (int i = tid; i < 512; i += 256) {
            int row = i >> 2, ch = i & 3;
            *(uint4*)&As[row][ch * 8] = *(const uint4*)&A[(m0 + row) * K + kt + ch * 8];
            *(uint4*)&Bs[row][ch * 8] = *(const uint4*)&Bt[(n0 + row) * K + kt + ch * 8];
        }
        __syncthreads();
        bf16x8 af[4], bfr[4];
        #pragma unroll
        for (int t = 0; t < 4; ++t) {
            af[t]  = *(const bf16x8*)&As[wm + t * 16 + lr][lg * 8];
            bfr[t] = *(const bf16x8*)&Bs[wn + t * 16 + lr][lg * 8];
        }
        #pragma unroll
        for (int i2 = 0; i2 < 4; ++i2)
            #pragma unroll
            for (int j2 = 0; j2 < 4; ++j2)
                acc[i2][j2] = __builtin_amdgcn_mfma_f32_16x16x32_bf16(af[i2], bfr[j2], acc[i2][j2], 0, 0, 0);
        __syncthreads();
    }
    #pragma unroll
    for (int i2 = 0; i2 < 4; ++i2)
        #pragma unroll
        for (int j2 = 0; j2 < 4; ++j2)
            #pragma unroll
            for (int r = 0; r < 4; ++r) {
                int row = m0 + wm + i2 * 16 + lg * 4 + r;
                int col = n0 + wn + j2 * 16 + lr;
                float v = acc[i2][j2][r];
                if (MODE == 0) {
                    ((float*)C)[row * N + col] = v;
                } else if (MODE == 1) {
                    int b = row >> 11, s = row & 2047, h = col >> 6, d = col & 63;
                    ((unsigned short*)C)[((b * H_ + h) * S_ + s) * DKV_ + d] = f2bf(v);
                } else {
                    int b = row >> 11, s = row & 2047, h = col >> 6, d = col & 63;
                    ((unsigned short*)C)[((b * H_ + h) * DKV_ + d) * S_ + s] = f2bf(v);
                }
            }
}

// ---------------- flash attention ----------------
// Q,K: bf16 [b][h][s][64]; Vt: bf16 [b][h][64][s]; out: bf16 [b*s][h*64+d]
__global__ __launch_bounds__(256) void flash_attn(const unsigned short* __restrict__ Q,
                                                  const unsigned short* __restrict__ Kg,
                                                  const unsigned short* __restrict__ Vt,
                                                  const float* __restrict__ bias_tab,
                                                  unsigned short* __restrict__ Out) {
    __shared__ alignas(16) unsigned short Ks[32][72];
    __shared__ alignas(16) unsigned short Vs[64][40];
    __shared__ alignas(16) unsigned short Ps[4][16][40];
    int tid = threadIdx.x, wid = tid >> 6, lane = tid & 63;
    int bh = blockIdx.y;             // b*16 + h
    int h = bh & 15;
    int q0 = blockIdx.x * 64 + wid * 16;
    int lr = lane & 15, lg = lane >> 4;

    const unsigned short* Qbase = Q + (bh * S_ + q0) * DKV_;
    bf16x8 qf0 = *(const bf16x8*)&Qbase[lr * DKV_ + lg * 8];
    bf16x8 qf1 = *(const bf16x8*)&Qbase[lr * DKV_ + 32 + lg * 8];

    f32x4 o[4] = {};
    float mrun[4], lrun[4];
    #pragma unroll
    for (int r = 0; r < 4; ++r) { mrun[r] = -INFINITY; lrun[r] = 0.f; }
    const float* btab = bias_tab + h * 4096 + 2048;

    for (int kt = 0; kt < S_; kt += 32) {
        {   // stage K tile [32 keys][64 d] and Vt tile [64 d][32 keys]
            int row = tid >> 3, ch = tid & 7;
            *(uint4*)&Ks[row][ch * 8] = *(const uint4*)&Kg[(bh * S_ + kt + row) * DKV_ + ch * 8];
            int vrow = tid >> 2, vch = tid & 3;
            *(uint4*)&Vs[vrow][vch * 8] = *(const uint4*)&Vt[(bh * DKV_ + vrow) * S_ + kt + vch * 8];
        }
        __syncthreads();
        // QK^T : 16 q x 32 keys
        f32x4 sa[2] = {};
        #pragma unroll
        for (int nt = 0; nt < 2; ++nt) {
            bf16x8 kf0 = *(const bf16x8*)&Ks[nt * 16 + lr][lg * 8];
            bf16x8 kf1 = *(const bf16x8*)&Ks[nt * 16 + lr][32 + lg * 8];
            sa[nt] = __builtin_amdgcn_mfma_f32_16x16x32_bf16(qf0, kf0, sa[nt], 0, 0, 0);
            sa[nt] = __builtin_amdgcn_mfma_f32_16x16x32_bf16(qf1, kf1, sa[nt], 0, 0, 0);
        }
        // bias + online softmax (C layout: col=lane&15 -> key, row=(lane>>4)*4+r -> q)
        float sv[2][4];
        #pragma unroll
        for (int r = 0; r < 4; ++r) {
            int q = q0 + lg * 4 + r;
            float vmax = -INFINITY;
            #pragma unroll
            for (int nt = 0; nt < 2; ++nt) {
                int key = kt + nt * 16 + lr;
                float s = sa[nt][r] + btab[key - q];
                sv[nt][r] = s;
                vmax = fmaxf(vmax, s);
            }
            #pragma unroll
            for (int mm = 1; mm < 16; mm <<= 1)
                vmax = fmaxf(vmax, __shfl_xor(vmax, mm));
            float mnew = fmaxf(mrun[r], vmax);
            float scale = __expf(mrun[r] - mnew);
            float psum = 0.f;
            #pragma unroll
            for (int nt = 0; nt < 2; ++nt) {
                float p = __expf(sv[nt][r] - mnew);
                sv[nt][r] = p;
                psum += p;
            }
            #pragma unroll
            for (int mm = 1; mm < 16; mm <<= 1)
                psum += __shfl_xor(psum, mm);
            lrun[r] = lrun[r] * scale + psum;
            mrun[r] = mnew;
            #pragma unroll
            for (int dt = 0; dt < 4; ++dt) o[dt][r] *= scale;
            #pragma unroll
            for (int nt = 0; nt < 2; ++nt)
                Ps[wid][lg * 4 + r][nt * 16 + lr] = f2bf(sv[nt][r]);
        }
        // PV: P [16 q][32 keys] x V [32 keys][64 d]
        bf16x8 pf = *(const bf16x8*)&Ps[wid][lr][lg * 8];
        #pragma unroll
        for (int dt = 0; dt < 4; ++dt) {
            bf16x8 vf = *(const bf16x8*)&Vs[dt * 16 + lr][lg * 8];
            o[dt] = __builtin_amdgcn_mfma_f32_16x16x32_bf16(pf, vf, o[dt], 0, 0, 0);
        }
        __syncthreads();
    }
    int b = bh >> 4;
    #pragma unroll
    for (int dt = 0; dt < 4; ++dt)
        #pragma unroll
        for (int r = 0; r < 4; ++r) {
            int q = q0 + lg * 4 + r;
            float v = o[dt][r] / lrun[r];
            Out[(b * S_ + q) * INNER_ + h * DKV_ + dt * 16 + lr] = f2bf(v);
        }
}

extern "C" void kernel_launch(void* const* d_in, const int* in_sizes, int n_in,
                              void* d_out, int out_size, void* d_ws, size_t ws_size,
                              hipStream_t stream) {
    const float* hs = (const float*)d_in[0];
    const float* wq = (const float*)d_in[1];
    const float* wk = (const float*)d_in[2];
    const float* wv = (const float*)d_in[3];
    const float* wo = (const float*)d_in[4];
    const float* rb = (const float*)d_in[5];

    char* ws = (char*)d_ws;
    unsigned short* Abf = (unsigned short*)(ws);                 // 8 MB  [4096][1024]
    unsigned short* Wqt = (unsigned short*)(ws + (8u  << 20));   // 2 MB  [1024][1024]
    unsigned short* Wkt = (unsigned short*)(ws + (10u << 20));
    unsigned short* Wvt = (unsigned short*)(ws + (12u << 20));
    unsigned short* Wot = (unsigned short*)(ws + (14u << 20));
    unsigned short* Qb  = (unsigned short*)(ws + (16u << 20));   // 8 MB  [b][h][s][64]
    unsigned short* Kb  = (unsigned short*)(ws + (24u << 20));   // 8 MB
    unsigned short* Vtb = (unsigned short*)(ws + (32u << 20));   // 8 MB  [b][h][64][s]
    unsigned short* AOb = (unsigned short*)(ws + (40u << 20));   // 8 MB  [4096][1024]
    float*          Btab = (float*)(ws + (48u << 20));           // 256 KB [16][4096]

    cvt_bf16<<<4096, 256, 0, stream>>>(hs, Abf, M_ * D_);
    transp_bf16<<<dim3(16, 16, 4), 256, 0, stream>>>(wq, wk, wv, wo, Wqt, Wkt, Wvt, Wot);
    bias_kernel<<<256, 256, 0, stream>>>(rb, Btab);

    gemm128<1><<<dim3(8, 32), 256, 0, stream>>>(Abf, Wqt, Qb,  M_, INNER_, D_);
    gemm128<1><<<dim3(8, 32), 256, 0, stream>>>(Abf, Wkt, Kb,  M_, INNER_, D_);
    gemm128<2><<<dim3(8, 32), 256, 0, stream>>>(Abf, Wvt, Vtb, M_, INNER_, D_);

    flash_attn<<<dim3(32, 32), 256, 0, stream>>>(Qb, Kb, Vtb, Btab, AOb);

    gemm128<0><<<dim3(8, 32), 256, 0, stream>>>(AOb, Wot, (float*)d_out, M_, D_, INNER_);
}

// Round 2
// 225.426 us; speedup vs baseline: 1.3788x; 1.3788x over previous
//
#include <hip/hip_runtime.h>
#include <hip/hip_bf16.h>

#define B_ 2
#define S_ 2048
#define D_ 1024
#define H_ 16
#define DKV_ 64
#define INNER_ 1024
#define M_ (B_*S_)   // 4096

typedef unsigned short ushort_t;
typedef __bf16 bf16x8 __attribute__((ext_vector_type(8)));
typedef __bf16 bf16x4 __attribute__((ext_vector_type(4)));
typedef float f32x4 __attribute__((ext_vector_type(4)));

__device__ __forceinline__ unsigned short f2bf(float f) {
    unsigned int u = __builtin_bit_cast(unsigned int, f);
    unsigned int r = (u + 0x7fffu + ((u >> 16) & 1u)) >> 16;
    return (unsigned short)r;
}

// ---------------- fp32 -> bf16 convert (hidden states) ----------------
__global__ __launch_bounds__(256) void cvt_bf16(const float* __restrict__ in,
                                                unsigned short* __restrict__ out, int n) {
    int i = (blockIdx.x * 256 + threadIdx.x) * 4;
    if (i < n) {
        float4 v = *(const float4*)&in[i];
        ushort4 o;
        o.x = f2bf(v.x); o.y = f2bf(v.y); o.z = f2bf(v.z); o.w = f2bf(v.w);
        *(ushort4*)&out[i] = o;
    }
}

// ---------------- transpose+convert weights: Wt[n][k] = (bf16)W[k][n] ----------------
__global__ __launch_bounds__(256) void transp_bf16(
        const float* __restrict__ s0, const float* __restrict__ s1,
        const float* __restrict__ s2, const float* __restrict__ s3,
        unsigned short* __restrict__ d0, unsigned short* __restrict__ d1,
        unsigned short* __restrict__ d2, unsigned short* __restrict__ d3) {
    const float* srcs[4] = {s0, s1, s2, s3};
    unsigned short* dsts[4] = {d0, d1, d2, d3};
    const float* src = srcs[blockIdx.z];
    unsigned short* dst = dsts[blockIdx.z];
    __shared__ float t[64][65];
    int k0 = blockIdx.y * 64, n0 = blockIdx.x * 64;
    for (int i = threadIdx.x; i < 4096; i += 256) {
        int r = i >> 6, c = i & 63;
        t[r][c] = src[(k0 + r) * 1024 + n0 + c];
    }
    __syncthreads();
    for (int i = threadIdx.x; i < 4096; i += 256) {
        int r = i >> 6, c = i & 63;
        dst[(n0 + r) * 1024 + k0 + c] = f2bf(t[c][r]);
    }
}

// ---------------- T5 relative bias table: btab[h][rel+2048] (pre-scaled by log2e) ----------------
__global__ __launch_bounds__(256) void bias_kernel(const float* __restrict__ rb,
                                                   float* __restrict__ btab) {
    int idx = blockIdx.x * 256 + threadIdx.x;   // 0..65535
    int h = idx >> 12, pos = idx & 4095;
    int rel = pos - 2048;
    int bb = rel > 0 ? 16 : 0;
    int rp = rel < 0 ? -rel : rel;
    int bucket;
    if (rp < 8) bucket = bb + rp;
    else {
        int v = 8 + (int)(logf((float)rp * 0.125f) / 2.7725887f * 8.0f);
        bucket = bb + (v < 15 ? v : 15);
    }
    btab[idx] = rb[bucket * 16 + h] * 1.4426950408889634f;
}

// ---------------- 128x128 MFMA GEMM, A [M][K] bf16, Bt [N][K] bf16 ----------------
template<int MODE>
__global__ __launch_bounds__(256) void gemm128(const unsigned short* __restrict__ A,
                                               const unsigned short* __restrict__ Bt,
                                               void* __restrict__ C,
                                               int M, int N, int K) {
    __shared__ alignas(16) unsigned short As[128][40];
    __shared__ alignas(16) unsigned short Bs[128][40];
    int tid = threadIdx.x;
    int m0 = blockIdx.y * 128, n0 = blockIdx.x * 128;
    int wid = tid >> 6, lane = tid & 63;
    int wm = (wid >> 1) * 64, wn = (wid & 1) * 64;
    int lr = lane & 15, lg = lane >> 4;
    f32x4 acc[4][4] = {};
    for (int kt = 0; kt < K; kt += 32) {
        #pragma unroll
        for (int i = tid; i < 512; i += 256) {
            int row = i >> 2, ch = i & 3;
            *(uint4*)&As[row][ch * 8] = *(const uint4*)&A[(m0 + row) * K + kt + ch * 8];
            *(uint4*)&Bs[row][ch * 8] = *(const uint4*)&Bt[(n0 + row) * K + kt + ch * 8];
        }
        __syncthreads();
        bf16x8 af[4], bfr[4];
        #pragma unroll
        for (int t = 0; t < 4; ++t) {
            af[t]  = *(const bf16x8*)&As[wm + t * 16 + lr][lg * 8];
            bfr[t] = *(const bf16x8*)&Bs[wn + t * 16 + lr][lg * 8];
        }
        #pragma unroll
        for (int i2 = 0; i2 < 4; ++i2)
            #pragma unroll
            for (int j2 = 0; j2 < 4; ++j2)
                acc[i2][j2] = __builtin_amdgcn_mfma_f32_16x16x32_bf16(af[i2], bfr[j2], acc[i2][j2], 0, 0, 0);
        __syncthreads();
    }
    #pragma unroll
    for (int i2 = 0; i2 < 4; ++i2)
        #pragma unroll
        for (int j2 = 0; j2 < 4; ++j2)
            #pragma unroll
            for (int r = 0; r < 4; ++r) {
                int row = m0 + wm + i2 * 16 + lg * 4 + r;
                int col = n0 + wn + j2 * 16 + lr;
                float v = acc[i2][j2][r];
                if (MODE == 0) {
                    ((float*)C)[row * N + col] = v;
                } else if (MODE == 1) {
                    int b = row >> 11, s = row & 2047, h = col >> 6, d = col & 63;
                    ((unsigned short*)C)[((b * H_ + h) * S_ + s) * DKV_ + d] = f2bf(v);
                } else {
                    int b = row >> 11, s = row & 2047, h = col >> 6, d = col & 63;
                    ((unsigned short*)C)[((b * H_ + h) * DKV_ + d) * S_ + s] = f2bf(v);
                }
            }
}

// ---------------- flash attention, swapped-operand MFMA ----------------
// Q,K: bf16 [b][h][s][64]; Vt: bf16 [b][h][64][s]; out: bf16 [b*s][h*64+d]
// QK^T: mfma(K_frag, Q_frag) -> C[key][q], lane holds 16 scores for q = lane&15.
// PV:   mfma(V_frag, P_frag) -> C[d][q], stats stay lane-local (q = lane&15).
__global__ __launch_bounds__(256) void flash_attn(const unsigned short* __restrict__ Q,
                                                  const unsigned short* __restrict__ Kg,
                                                  const unsigned short* __restrict__ Vt,
                                                  const float* __restrict__ bias_tab,
                                                  unsigned short* __restrict__ Out) {
    __shared__ alignas(16) unsigned short Ks[64][72];
    __shared__ alignas(16) unsigned short Vs[64][72];
    __shared__ alignas(16) unsigned short Ps[4][16][72];
    __shared__ float LbS[2112];
    int tid = threadIdx.x, wid = tid >> 6, lane = tid & 63;
    int bh = blockIdx.y;             // b*16 + h
    int h = bh & 15, b = bh >> 4;
    int q0b = blockIdx.x * 64;
    int q0w = q0b + wid * 16;
    int lr = lane & 15, lg = lane >> 4;

    // stage this block's bias slice: LbS[i] = btab[h][(2048 - q0b - 63) + i]
    {
        const float* bsrc = bias_tab + h * 4096 + 2048 - q0b - 63;
        for (int i = tid; i < 2111; i += 256) LbS[i] = bsrc[i];
    }

    const unsigned short* Qbase = Q + (bh * S_ + q0w) * DKV_;
    bf16x8 qf0 = *(const bf16x8*)&Qbase[lr * DKV_ + lg * 8];
    bf16x8 qf1 = *(const bf16x8*)&Qbase[lr * DKV_ + 32 + lg * 8];

    f32x4 o[4] = {};
    float mrun = -INFINITY, lrun = 0.f;
    const int bbase = 63 - wid * 16 + 4 * lg - lr;   // + kt + nt*16 + r -> LbS index

    for (int kt = 0; kt < S_; kt += 64) {
        // stage K [64 keys][64 d] and Vt [64 d][64 keys]
        #pragma unroll
        for (int j = 0; j < 2; ++j) {
            int idx = tid + j * 256;
            int row = idx >> 3, ch = idx & 7;
            *(uint4*)&Ks[row][ch * 8] = *(const uint4*)&Kg[(bh * S_ + kt + row) * DKV_ + ch * 8];
            *(uint4*)&Vs[row][ch * 8] = *(const uint4*)&Vt[(bh * DKV_ + row) * S_ + kt + ch * 8];
        }
        __syncthreads();
        // QK^T swapped
        f32x4 sa[4] = {};
        #pragma unroll
        for (int nt = 0; nt < 4; ++nt) {
            bf16x8 kf0 = *(const bf16x8*)&Ks[nt * 16 + lr][lg * 8];
            bf16x8 kf1 = *(const bf16x8*)&Ks[nt * 16 + lr][32 + lg * 8];
            sa[nt] = __builtin_amdgcn_mfma_f32_16x16x32_bf16(kf0, qf0, sa[nt], 0, 0, 0);
            sa[nt] = __builtin_amdgcn_mfma_f32_16x16x32_bf16(kf1, qf1, sa[nt], 0, 0, 0);
        }
        // online softmax in exp2 domain; lane owns q = lr, 16 scores in-register
        float p[4][4];
        float mt = -INFINITY;
        const int bi = kt + bbase;
        #pragma unroll
        for (int nt = 0; nt < 4; ++nt)
            #pragma unroll
            for (int r = 0; r < 4; ++r) {
                float s2 = fmaf(sa[nt][r], 1.4426950408889634f, LbS[bi + nt * 16 + r]);
                p[nt][r] = s2;
                mt = fmaxf(mt, s2);
            }
        mt = fmaxf(mt, __shfl_xor(mt, 16));
        mt = fmaxf(mt, __shfl_xor(mt, 32));
        float mnew = fmaxf(mrun, mt);
        float scale = __builtin_amdgcn_exp2f(mrun - mnew);
        float psum = 0.f;
        #pragma unroll
        for (int nt = 0; nt < 4; ++nt)
            #pragma unroll
            for (int r = 0; r < 4; ++r) {
                float e = __builtin_amdgcn_exp2f(p[nt][r] - mnew);
                p[nt][r] = e;
                psum += e;
            }
        psum += __shfl_xor(psum, 16);
        psum += __shfl_xor(psum, 32);
        lrun = lrun * scale + psum;
        mrun = mnew;
        #pragma unroll
        for (int dt = 0; dt < 4; ++dt)
            #pragma unroll
            for (int r = 0; r < 4; ++r)
                o[dt][r] *= scale;
        // P -> per-wave LDS region (no barrier: wave-coherent)
        #pragma unroll
        for (int nt = 0; nt < 4; ++nt) {
            bf16x4 pv;
            pv[0] = (__bf16)p[nt][0]; pv[1] = (__bf16)p[nt][1];
            pv[2] = (__bf16)p[nt][2]; pv[3] = (__bf16)p[nt][3];
            *(bf16x4*)&Ps[wid][lr][nt * 16 + lg * 4] = pv;
        }
        // PV swapped: o[dt] = V_frag(dt) x P_frag
        bf16x8 pf0 = *(const bf16x8*)&Ps[wid][lr][lg * 8];
        bf16x8 pf1 = *(const bf16x8*)&Ps[wid][lr][32 + lg * 8];
        #pragma unroll
        for (int dt = 0; dt < 4; ++dt) {
            bf16x8 vf0 = *(const bf16x8*)&Vs[dt * 16 + lr][lg * 8];
            bf16x8 vf1 = *(const bf16x8*)&Vs[dt * 16 + lr][32 + lg * 8];
            o[dt] = __builtin_amdgcn_mfma_f32_16x16x32_bf16(vf0, pf0, o[dt], 0, 0, 0);
            o[dt] = __builtin_amdgcn_mfma_f32_16x16x32_bf16(vf1, pf1, o[dt], 0, 0, 0);
        }
        __syncthreads();
    }
    // epilogue: normalize (stats already lane-aligned with o), transpose via LDS, coalesced store
    float linv = 1.f / lrun;
    #pragma unroll
    for (int dt = 0; dt < 4; ++dt) {
        bf16x4 ov;
        ov[0] = (__bf16)(o[dt][0] * linv); ov[1] = (__bf16)(o[dt][1] * linv);
        ov[2] = (__bf16)(o[dt][2] * linv); ov[3] = (__bf16)(o[dt][3] * linv);
        *(bf16x4*)&Ps[wid][lr][dt * 16 + lg * 4] = ov;
    }
    int row = lane >> 2, seg = lane & 3;
    uint4 v0 = *(uint4*)&Ps[wid][row][seg * 16];
    uint4 v1 = *(uint4*)&Ps[wid][row][seg * 16 + 8];
    unsigned short* dst = Out + ((size_t)(b * S_ + q0w + row) * INNER_) + h * DKV_ + seg * 16;
    *(uint4*)&dst[0] = v0;
    *(uint4*)&dst[8] = v1;
}

extern "C" void kernel_launch(void* const* d_in, const int* in_sizes, int n_in,
                              void* d_out, int out_size, void* d_ws, size_t ws_size,
                              hipStream_t stream) {
    const float* hs = (const float*)d_in[0];
    const float* wq = (const float*)d_in[1];
    const float* wk = (const float*)d_in[2];
    const float* wv = (const float*)d_in[3];
    const float* wo = (const float*)d_in[4];
    const float* rb = (const float*)d_in[5];

    char* ws = (char*)d_ws;
    unsigned short* Abf = (unsigned short*)(ws);                 // 8 MB  [4096][1024]
    unsigned short* Wqt = (unsigned short*)(ws + (8u  << 20));   // 2 MB  [1024][1024]
    unsigned short* Wkt = (unsigned short*)(ws + (10u << 20));
    unsigned short* Wvt = (unsigned short*)(ws + (12u << 20));
    unsigned short* Wot = (unsigned short*)(ws + (14u << 20));
    unsigned short* Qb  = (unsigned short*)(ws + (16u << 20));   // 8 MB  [b][h][s][64]
    unsigned short* Kb  = (unsigned short*)(ws + (24u << 20));   // 8 MB
    unsigned short* Vtb = (unsigned short*)(ws + (32u << 20));   // 8 MB  [b][h][64][s]
    unsigned short* AOb = (unsigned short*)(ws + (40u << 20));   // 8 MB  [4096][1024]
    float*          Btab = (float*)(ws + (48u << 20));           // 256 KB [16][4096]

    cvt_bf16<<<4096, 256, 0, stream>>>(hs, Abf, M_ * D_);
    transp_bf16<<<dim3(16, 16, 4), 256, 0, stream>>>(wq, wk, wv, wo, Wqt, Wkt, Wvt, Wot);
    bias_kernel<<<256, 256, 0, stream>>>(rb, Btab);

    gemm128<1><<<dim3(8, 32), 256, 0, stream>>>(Abf, Wqt, Qb,  M_, INNER_, D_);
    gemm128<1><<<dim3(8, 32), 256, 0, stream>>>(Abf, Wkt, Kb,  M_, INNER_, D_);
    gemm128<2><<<dim3(8, 32), 256, 0, stream>>>(Abf, Wvt, Vtb, M_, INNER_, D_);

    flash_attn<<<dim3(32, 32), 256, 0, stream>>>(Qb, Kb, Vtb, Btab, AOb);

    gemm128<0><<<dim3(8, 32), 256, 0, stream>>>(AOb, Wot, (float*)d_out, M_, D_, INNER_);
}

// Round 3
// 155.177 us; speedup vs baseline: 2.0031x; 1.4527x over previous
//
#include <hip/hip_runtime.h>
#include <hip/hip_bf16.h>

#define B_ 2
#define S_ 2048
#define D_ 1024
#define H_ 16
#define DKV_ 64
#define INNER_ 1024
#define M_ (B_*S_)   // 4096

typedef unsigned short ushort_t;
typedef unsigned int u32;
typedef __bf16 bf16x8 __attribute__((ext_vector_type(8)));
typedef __bf16 bf16x4 __attribute__((ext_vector_type(4)));
typedef float f32x4 __attribute__((ext_vector_type(4)));

#define VMCNT0 asm volatile("s_waitcnt vmcnt(0)" ::: "memory")
#define LOG2E 1.4426950408889634f

__device__ __forceinline__ unsigned short f2bf(float f) {
    unsigned int u = __builtin_bit_cast(unsigned int, f);
    unsigned int r = (u + 0x7fffu + ((u >> 16) & 1u)) >> 16;
    return (unsigned short)r;
}

__device__ __forceinline__ void gload16(const ushort_t* g, ushort_t* l) {
    __builtin_amdgcn_global_load_lds(
        (const __attribute__((address_space(1))) u32*)g,
        (__attribute__((address_space(3))) u32*)l, 16, 0, 0);
}

// ---------------- fp32 -> bf16 convert ----------------
__global__ __launch_bounds__(256) void cvt_bf16(const float* __restrict__ in,
                                                unsigned short* __restrict__ out, int n) {
    int i = (blockIdx.x * 256 + threadIdx.x) * 4;
    if (i < n) {
        float4 v = *(const float4*)&in[i];
        ushort4 o;
        o.x = f2bf(v.x); o.y = f2bf(v.y); o.z = f2bf(v.z); o.w = f2bf(v.w);
        *(ushort4*)&out[i] = o;
    }
}

// ---------------- transpose+convert weights: Wt[n][k] = (bf16)W[k][n] ----------------
__global__ __launch_bounds__(256) void transp_bf16(
        const float* __restrict__ s0, const float* __restrict__ s1,
        const float* __restrict__ s2, const float* __restrict__ s3,
        unsigned short* __restrict__ d0, unsigned short* __restrict__ d1,
        unsigned short* __restrict__ d2, unsigned short* __restrict__ d3) {
    const float* srcs[4] = {s0, s1, s2, s3};
    unsigned short* dsts[4] = {d0, d1, d2, d3};
    const float* src = srcs[blockIdx.z];
    unsigned short* dst = dsts[blockIdx.z];
    __shared__ float t[64][65];
    int k0 = blockIdx.y * 64, n0 = blockIdx.x * 64;
    for (int i = threadIdx.x; i < 4096; i += 256) {
        int r = i >> 6, c = i & 63;
        t[r][c] = src[(k0 + r) * 1024 + n0 + c];
    }
    __syncthreads();
    for (int i = threadIdx.x; i < 4096; i += 256) {
        int r = i >> 6, c = i & 63;
        dst[(n0 + r) * 1024 + k0 + c] = f2bf(t[c][r]);
    }
}

// ---------------- T5 relative bias table, pre-scaled by log2e ----------------
__global__ __launch_bounds__(256) void bias_kernel(const float* __restrict__ rb,
                                                   float* __restrict__ btab) {
    int idx = blockIdx.x * 256 + threadIdx.x;   // 0..65535
    int h = idx >> 12, pos = idx & 4095;
    int rel = pos - 2048;
    int bb = rel > 0 ? 16 : 0;
    int rp = rel < 0 ? -rel : rel;
    int bucket;
    if (rp < 8) bucket = bb + rp;
    else {
        int v = 8 + (int)(logf((float)rp * 0.125f) / 2.7725887f * 8.0f);
        bucket = bb + (v < 15 ? v : 15);
    }
    btab[idx] = rb[bucket * 16 + h] * LOG2E;
}

// ---------------- fused QKV GEMM: A[4096][1024] x {WQ,WK,WV}^T, 128x128 tile, BK=64 ----------------
__global__ __launch_bounds__(256) void gemm_qkv(const ushort_t* __restrict__ A,
        const ushort_t* __restrict__ WQ, const ushort_t* __restrict__ WK, const ushort_t* __restrict__ WV,
        ushort_t* __restrict__ Qb, ushort_t* __restrict__ Kb, ushort_t* __restrict__ Vtb) {
    __shared__ alignas(16) ushort_t As[128][64];
    __shared__ alignas(16) ushort_t Bs[128][64];
    int tid = threadIdx.x, wid = tid >> 6, lane = tid & 63;
    int linear = blockIdx.x;                    // 768 blocks
    int swz = (linear & 7) * 96 + (linear >> 3);
    int m0 = (swz / 24) * 128;
    int nblk = swz % 24;
    int sel = nblk >> 3;                        // 0=Q 1=K 2=V
    const ushort_t* Bt = sel == 0 ? WQ : (sel == 1 ? WK : WV);
    int n0 = (nblk & 7) * 128;
    int lr = lane & 15, lg = lane >> 4;
    int wm = (wid >> 1) * 64, wn = (wid & 1) * 64;
    int srow = tid >> 3, sp = tid & 7;
    int scol = (sp ^ (srow & 7)) * 8;           // pre-swizzled source column
    int cR0 = (lg ^ (lr & 7)) * 8;              // swizzled read cols, halves 0/1
    int cR1 = ((4 + lg) ^ (lr & 7)) * 8;
    const ushort_t* Abase = A + (size_t)m0 * 1024 + scol;
    const ushort_t* Bbase = Bt + (size_t)n0 * 1024 + scol;
    f32x4 acc[4][4] = {};
    for (int kt = 0; kt < 1024; kt += 64) {
        #pragma unroll
        for (int j = 0; j < 4; ++j) {
            int row = j * 32 + srow;
            gload16(Abase + row * 1024 + kt, &As[0][0] + (j * 256 + tid) * 8);
            gload16(Bbase + row * 1024 + kt, &Bs[0][0] + (j * 256 + tid) * 8);
        }
        VMCNT0;
        __syncthreads();
        bf16x8 af[4][2], bfr[4][2];
        #pragma unroll
        for (int t = 0; t < 4; ++t) {
            af[t][0]  = *(const bf16x8*)&As[wm + t * 16 + lr][cR0];
            af[t][1]  = *(const bf16x8*)&As[wm + t * 16 + lr][cR1];
            bfr[t][0] = *(const bf16x8*)&Bs[wn + t * 16 + lr][cR0];
            bfr[t][1] = *(const bf16x8*)&Bs[wn + t * 16 + lr][cR1];
        }
        #pragma unroll
        for (int hh = 0; hh < 2; ++hh)
            #pragma unroll
            for (int i2 = 0; i2 < 4; ++i2)
                #pragma unroll
                for (int j2 = 0; j2 < 4; ++j2)
                    acc[i2][j2] = __builtin_amdgcn_mfma_f32_16x16x32_bf16(af[i2][hh], bfr[j2][hh], acc[i2][j2], 0, 0, 0);
        __syncthreads();
    }
    #pragma unroll
    for (int i2 = 0; i2 < 4; ++i2)
        #pragma unroll
        for (int j2 = 0; j2 < 4; ++j2) {
            int col = n0 + wn + j2 * 16 + lr;
            int hh = col >> 6, d = col & 63;
            if (sel < 2) {
                ushort_t* dst = sel == 0 ? Qb : Kb;
                #pragma unroll
                for (int r = 0; r < 4; ++r) {
                    int row = m0 + wm + i2 * 16 + lg * 4 + r;
                    int b = row >> 11, s = row & 2047;
                    dst[(((size_t)(b * H_ + hh) * S_ + s)) * DKV_ + d] = f2bf(acc[i2][j2][r]);
                }
            } else {
                int row0 = m0 + wm + i2 * 16 + lg * 4;
                int b = row0 >> 11, s0 = row0 & 2047;
                ushort4 sv;
                sv.x = f2bf(acc[i2][j2][0]); sv.y = f2bf(acc[i2][j2][1]);
                sv.z = f2bf(acc[i2][j2][2]); sv.w = f2bf(acc[i2][j2][3]);
                *(ushort4*)&Vtb[((size_t)(b * H_ + hh) * DKV_ + d) * S_ + s0] = sv;
            }
        }
}

// ---------------- output projection GEMM: 64x128 tile, BK=64, fp32 out ----------------
__global__ __launch_bounds__(256) void gemm_out(const ushort_t* __restrict__ A,
                                                const ushort_t* __restrict__ Bt,
                                                float* __restrict__ C) {
    __shared__ alignas(16) ushort_t As[64][64];
    __shared__ alignas(16) ushort_t Bs[128][64];
    int tid = threadIdx.x, wid = tid >> 6, lane = tid & 63;
    int linear = blockIdx.x;                    // 512 blocks
    int swz = (linear & 7) * 64 + (linear >> 3);
    int m0 = (swz >> 3) * 64, n0 = (swz & 7) * 128;
    int lr = lane & 15, lg = lane >> 4;
    int wn = wid * 32;
    int srow = tid >> 3, sp = tid & 7;
    int scol = (sp ^ (srow & 7)) * 8;
    int cR0 = (lg ^ (lr & 7)) * 8;
    int cR1 = ((4 + lg) ^ (lr & 7)) * 8;
    const ushort_t* Abase = A + (size_t)m0 * 1024 + scol;
    const ushort_t* Bbase = Bt + (size_t)n0 * 1024 + scol;
    f32x4 acc[4][2] = {};
    for (int kt = 0; kt < 1024; kt += 64) {
        #pragma unroll
        for (int j = 0; j < 2; ++j) {
            int row = j * 32 + srow;
            gload16(Abase + row * 1024 + kt, &As[0][0] + (j * 256 + tid) * 8);
        }
        #pragma unroll
        for (int j = 0; j < 4; ++j) {
            int row = j * 32 + srow;
            gload16(Bbase + row * 1024 + kt, &Bs[0][0] + (j * 256 + tid) * 8);
        }
        VMCNT0;
        __syncthreads();
        bf16x8 af[4][2], bfr[2][2];
        #pragma unroll
        for (int t = 0; t < 4; ++t) {
            af[t][0] = *(const bf16x8*)&As[t * 16 + lr][cR0];
            af[t][1] = *(const bf16x8*)&As[t * 16 + lr][cR1];
        }
        #pragma unroll
        for (int j = 0; j < 2; ++j) {
            bfr[j][0] = *(const bf16x8*)&Bs[wn + j * 16 + lr][cR0];
            bfr[j][1] = *(const bf16x8*)&Bs[wn + j * 16 + lr][cR1];
        }
        #pragma unroll
        for (int hh = 0; hh < 2; ++hh)
            #pragma unroll
            for (int i2 = 0; i2 < 4; ++i2)
                #pragma unroll
                for (int j2 = 0; j2 < 2; ++j2)
                    acc[i2][j2] = __builtin_amdgcn_mfma_f32_16x16x32_bf16(af[i2][hh], bfr[j2][hh], acc[i2][j2], 0, 0, 0);
        __syncthreads();
    }
    #pragma unroll
    for (int i2 = 0; i2 < 4; ++i2)
        #pragma unroll
        for (int j2 = 0; j2 < 2; ++j2)
            #pragma unroll
            for (int r = 0; r < 4; ++r)
                C[(size_t)(m0 + i2 * 16 + lg * 4 + r) * 1024 + n0 + wn + j2 * 16 + lr] = acc[i2][j2][r];
}

// ---------------- flash attention: dbuf global_load_lds staging, 1 barrier/tile ----------------
__global__ __launch_bounds__(256) void flash_attn(const ushort_t* __restrict__ Q,
                                                  const ushort_t* __restrict__ Kg,
                                                  const ushort_t* __restrict__ Vt,
                                                  const float* __restrict__ bias_tab,
                                                  ushort_t* __restrict__ Out) {
    __shared__ alignas(16) ushort_t Ks[2][64][64];
    __shared__ alignas(16) ushort_t Vs[2][64][64];
    __shared__ alignas(16) ushort_t Ps[4][16][64];
    __shared__ float LbS[2112];
    int tid = threadIdx.x, wid = tid >> 6, lane = tid & 63;
    int linear = blockIdx.x;                 // 1024 blocks
    int swz = (linear & 7) * 128 + (linear >> 3);
    int bh = swz >> 5, qblk = swz & 31;
    int h = bh & 15, b = bh >> 4;
    int q0b = qblk * 64, q0w = q0b + wid * 16;
    int lr = lane & 15, lg = lane >> 4;

    // bias slice for this q-block
    {
        const float* bsrc = bias_tab + h * 4096 + 2048 - q0b - 63;
        for (int i = tid; i < 2111; i += 256) LbS[i] = bsrc[i];
    }

    const ushort_t* Qbase = Q + ((size_t)bh * S_ + q0w) * DKV_;
    bf16x8 qf0 = *(const bf16x8*)&Qbase[lr * DKV_ + lg * 8];
    bf16x8 qf1 = *(const bf16x8*)&Qbase[lr * DKV_ + 32 + lg * 8];

    // staging geometry (pre-swizzled source)
    int srow = tid >> 3, sp = tid & 7;
    int kc = (sp ^ (srow & 7)) * 8;
    const ushort_t* Ksrc = Kg + (size_t)bh * S_ * DKV_ + kc;
    const ushort_t* Vsrc = Vt + (size_t)bh * DKV_ * S_ + kc;
    // swizzled fragment-read columns
    int c0 = (lg ^ (lr & 7)) * 8;
    int c1 = ((4 + lg) ^ (lr & 7)) * 8;
    int pxor = (lr & 7) << 4;

    f32x4 o[4] = {};
    float mrun = -INFINITY, lrun = 0.f;
    const int bbase = 63 - wid * 16 + 4 * lg - lr;

    auto stage = [&](int bufi, int kt) {
        ushort_t* kb = &Ks[bufi][0][0];
        ushort_t* vb = &Vs[bufi][0][0];
        gload16(Ksrc + (size_t)(kt + srow) * 64,      kb + tid * 8);
        gload16(Ksrc + (size_t)(kt + 32 + srow) * 64, kb + 2048 + tid * 8);
        gload16(Vsrc + (size_t)srow * S_ + kt,        vb + tid * 8);
        gload16(Vsrc + (size_t)(32 + srow) * S_ + kt, vb + 2048 + tid * 8);
    };

    stage(0, 0);
    VMCNT0;
    __syncthreads();
    int buf = 0;
    for (int kt = 0; kt < S_; kt += 64) {
        if (kt + 64 < S_) stage(buf ^ 1, kt + 64);
        // QK^T swapped: C[key][q]
        f32x4 sa[4] = {};
        #pragma unroll
        for (int nt = 0; nt < 4; ++nt) {
            bf16x8 kf0 = *(const bf16x8*)&Ks[buf][nt * 16 + lr][c0];
            bf16x8 kf1 = *(const bf16x8*)&Ks[buf][nt * 16 + lr][c1];
            sa[nt] = __builtin_amdgcn_mfma_f32_16x16x32_bf16(kf0, qf0, sa[nt], 0, 0, 0);
            sa[nt] = __builtin_amdgcn_mfma_f32_16x16x32_bf16(kf1, qf1, sa[nt], 0, 0, 0);
        }
        // online softmax, exp2 domain, defer-max
        float p[4][4];
        float mt = -INFINITY;
        const int bi = kt + bbase;
        #pragma unroll
        for (int nt = 0; nt < 4; ++nt)
            #pragma unroll
            for (int r = 0; r < 4; ++r) {
                float s2 = fmaf(sa[nt][r], LOG2E, LbS[bi + nt * 16 + r]);
                p[nt][r] = s2;
                mt = fmaxf(mt, s2);
            }
        mt = fmaxf(mt, __shfl_xor(mt, 16));
        mt = fmaxf(mt, __shfl_xor(mt, 32));
        if (!__all(mt <= mrun + 8.f)) {
            float mnew = fmaxf(mrun, mt);
            float sc = __builtin_amdgcn_exp2f(mrun - mnew);
            mrun = mnew;
            lrun *= sc;
            #pragma unroll
            for (int dt = 0; dt < 4; ++dt)
                #pragma unroll
                for (int r = 0; r < 4; ++r)
                    o[dt][r] *= sc;
        }
        float psum = 0.f;
        #pragma unroll
        for (int nt = 0; nt < 4; ++nt)
            #pragma unroll
            for (int r = 0; r < 4; ++r) {
                float e = __builtin_amdgcn_exp2f(p[nt][r] - mrun);
                p[nt][r] = e;
                psum += e;
            }
        psum += __shfl_xor(psum, 16);
        psum += __shfl_xor(psum, 32);
        lrun += psum;
        // P -> per-wave swizzled LDS
        char* pbase = (char*)&Ps[wid][lr][0];
        #pragma unroll
        for (int nt = 0; nt < 4; ++nt) {
            bf16x4 pv;
            pv[0] = (__bf16)p[nt][0]; pv[1] = (__bf16)p[nt][1];
            pv[2] = (__bf16)p[nt][2]; pv[3] = (__bf16)p[nt][3];
            *(bf16x4*)(pbase + ((nt * 32 + lg * 8) ^ pxor)) = pv;
        }
        bf16x8 pf0 = *(const bf16x8*)(pbase + ((lg * 16) ^ pxor));
        bf16x8 pf1 = *(const bf16x8*)(pbase + ((64 + lg * 16) ^ pxor));
        // PV swapped: C[d][q]
        #pragma unroll
        for (int dt = 0; dt < 4; ++dt) {
            bf16x8 vf0 = *(const bf16x8*)&Vs[buf][dt * 16 + lr][c0];
            bf16x8 vf1 = *(const bf16x8*)&Vs[buf][dt * 16 + lr][c1];
            o[dt] = __builtin_amdgcn_mfma_f32_16x16x32_bf16(vf0, pf0, o[dt], 0, 0, 0);
            o[dt] = __builtin_amdgcn_mfma_f32_16x16x32_bf16(vf1, pf1, o[dt], 0, 0, 0);
        }
        VMCNT0;
        __syncthreads();
        buf ^= 1;
    }
    // epilogue: normalize, transpose via swizzled Ps, coalesced store
    float linv = 1.f / lrun;
    char* pbase = (char*)&Ps[wid][lr][0];
    #pragma unroll
    for (int dt = 0; dt < 4; ++dt) {
        bf16x4 ov;
        ov[0] = (__bf16)(o[dt][0] * linv); ov[1] = (__bf16)(o[dt][1] * linv);
        ov[2] = (__bf16)(o[dt][2] * linv); ov[3] = (__bf16)(o[dt][3] * linv);
        *(bf16x4*)(pbase + ((dt * 32 + lg * 8) ^ pxor)) = ov;
    }
    int row = lane >> 2, seg = lane & 3;
    int rxor = (row & 7) << 4;
    char* rbase = (char*)&Ps[wid][row][0];
    uint4 v0 = *(uint4*)(rbase + ((seg * 32) ^ rxor));
    uint4 v1 = *(uint4*)(rbase + ((seg * 32 + 16) ^ rxor));
    ushort_t* dst = Out + (size_t)(b * S_ + q0w + row) * INNER_ + h * DKV_ + seg * 16;
    *(uint4*)&dst[0] = v0;
    *(uint4*)&dst[8] = v1;
}

extern "C" void kernel_launch(void* const* d_in, const int* in_sizes, int n_in,
                              void* d_out, int out_size, void* d_ws, size_t ws_size,
                              hipStream_t stream) {
    const float* hs = (const float*)d_in[0];
    const float* wq = (const float*)d_in[1];
    const float* wk = (const float*)d_in[2];
    const float* wv = (const float*)d_in[3];
    const float* wo = (const float*)d_in[4];
    const float* rb = (const float*)d_in[5];

    char* ws = (char*)d_ws;
    unsigned short* Abf = (unsigned short*)(ws);                 // 8 MB  [4096][1024]
    unsigned short* Wqt = (unsigned short*)(ws + (8u  << 20));   // 2 MB  [1024][1024]
    unsigned short* Wkt = (unsigned short*)(ws + (10u << 20));
    unsigned short* Wvt = (unsigned short*)(ws + (12u << 20));
    unsigned short* Wot = (unsigned short*)(ws + (14u << 20));
    unsigned short* Qb  = (unsigned short*)(ws + (16u << 20));   // 8 MB  [b][h][s][64]
    unsigned short* Kb  = (unsigned short*)(ws + (24u << 20));   // 8 MB
    unsigned short* Vtb = (unsigned short*)(ws + (32u << 20));   // 8 MB  [b][h][64][s]
    unsigned short* AOb = (unsigned short*)(ws + (40u << 20));   // 8 MB  [4096][1024]
    float*          Btab = (float*)(ws + (48u << 20));           // 256 KB [16][4096]

    cvt_bf16<<<4096, 256, 0, stream>>>(hs, Abf, M_ * D_);
    transp_bf16<<<dim3(16, 16, 4), 256, 0, stream>>>(wq, wk, wv, wo, Wqt, Wkt, Wvt, Wot);
    bias_kernel<<<256, 256, 0, stream>>>(rb, Btab);

    gemm_qkv<<<768, 256, 0, stream>>>(Abf, Wqt, Wkt, Wvt, Qb, Kb, Vtb);

    flash_attn<<<1024, 256, 0, stream>>>(Qb, Kb, Vtb, Btab, AOb);

    gemm_out<<<512, 256, 0, stream>>>(AOb, Wot, (float*)d_out);
}